// Round 14
// baseline (115.520 us; speedup 1.0000x reference)
//
#include <hip/hip_runtime.h>

#define HID 256
#define K27 27

typedef __attribute__((ext_vector_type(8))) short    bf16x8;
typedef __attribute__((ext_vector_type(4))) float    f32x4;
typedef __attribute__((ext_vector_type(4))) unsigned u32x4;

static __device__ __forceinline__ unsigned short f2bf(float f) {
    union { float f; unsigned u; } v; v.f = f;   // cold path only (staging)
    return (unsigned short)((v.u + 0x7FFFu + ((v.u >> 16) & 1u)) >> 16);
}
static __device__ __forceinline__ unsigned pack2bf(float lo, float hi) {
    unsigned r;
    asm("v_cvt_pk_bf16_f32 %0, %1, %2" : "=v"(r) : "v"(lo), "v"(hi));
    return r;
}
static __device__ __forceinline__ bf16x8 as_bf16x8(u32x4 u) {
    return __builtin_bit_cast(bf16x8, u);
}
static __device__ __forceinline__ bf16x8 frag1(unsigned u) {
    u32x4 t = {u, 0u, 0u, 0u};
    return __builtin_bit_cast(bf16x8, t);
}
static __device__ __forceinline__ float lk(float x) {   // leaky_relu(0.01)
    return fmaxf(x, 0.01f * x);
}
// s += dpp_perm(s): VALU-only cross-lane add (verified v7/v10)
#define DPP_ADD(s, ctrl) \
    s += __builtin_bit_cast(float, __builtin_amdgcn_update_dpp( \
            0, __builtin_bit_cast(int, s), ctrl, 0xF, 0xF, true))

// v13 = v10 (verified 78us) widened to 4 tiles per iteration (2 outer iters):
// 4 independent L1->pack->L2 chains per kc step + 4 independent gather
// streams = intra-iteration ILP instead of cross-iteration pipelining (which
// spilled in v7/v12). No loop-carried state, all indices compile-time.
__global__ __launch_bounds__(256, 4) void mapnet_v13(
    const float* __restrict__ pos,      // (P,3)
    const int*   __restrict__ mapping,  // (P,2)
    const float* __restrict__ feats,    // (3,512,512)
    const float* __restrict__ W1,       // (256,3)
    const float* __restrict__ b1,       // (256)
    const float* __restrict__ W2,       // (27,256)
    const float* __restrict__ b2,       // (27)
    float* __restrict__ out)            // (P)
{
    __shared__ unsigned sW1f[16][64];   // [jt][lane]: pack2bf(W1val,0)  (4 KB)
    __shared__ bf16x8   sB[16][64];     // [kc*2+nt][lane]: L2 B-frags   (16 KB)

    const int tid = threadIdx.x;

    // ---- stage L1 A-fragments: lane (g,cc) of tile jt holds W1[16jt+cc][g] (g=3 -> b1)
    for (int e = tid; e < 1024; e += 256) {
        const int jt = e >> 6, l = e & 63;
        const int gg = l >> 4, cc = l & 15;
        const int j = jt * 16 + cc;
        const float val = (gg < 3) ? W1[3 * j + gg] : b1[j];
        sW1f[jt][l] = pack2bf(val, 0.0f);
    }
    // ---- stage L2 B-fragments, j-map matching L1 output: j = 32kc+16(e>>2)+4g+(e&3)
    for (int e = tid; e < 1024; e += 256) {
        const int kcnt = e >> 6, l = e & 63;
        const int kc = kcnt >> 1, nt = kcnt & 1;
        const int gg = l >> 4, cc = l & 15;
        const int n = nt * 16 + cc;
        const int jbase = kc * 32 + 4 * gg;
        u32x4 bb;
        #pragma unroll
        for (int i = 0; i < 4; ++i) {
            const int jlo = jbase + 16 * (i >> 1) + 2 * (i & 1);
            float f0 = 0.f, f1 = 0.f;
            if (n < K27) { f0 = W2[n * HID + jlo]; f1 = W2[n * HID + jlo + 1]; }
            bb[i] = (unsigned)f2bf(f0) | ((unsigned)f2bf(f1) << 16);
        }
        sB[kcnt][l] = as_bf16x8(bb);
    }
    __syncthreads();

    const int lane = tid & 63, wid = tid >> 6;
    const int g = lane >> 4, col = lane & 15;

    const float b2A = b2[col];
    const float b2B = (col < K27 - 16) ? b2[16 + col] : 0.0f;
    const int kA = col;
    const int cA = kA/9, dyA = (kA%9)/3 - 1, dxA = (kA%9)%3 - 1;
    const int kB = min(16 + col, K27 - 1);          // clamped -> valid addr; accB==0 there
    const int cB = kB/9, dyB = (kB%9)/3 - 1, dxB = (kB%9)%3 - 1;

    const float* fbaseA = feats + cA * (512*512);
    const float* fbaseB = feats + cB * (512*512);
    const int2*  map2   = (const int2*)mapping;

    const int w = blockIdx.x * 4 + wid;             // 0..8191

    for (int it = 0; it < 2; ++it) {
        const int base = (w * 8 + it * 4) * 16;     // 4 tiles of 16 px this iter

        // ---- L1 B-fragments (pos), one per tile ----
        bf16x8 pBf[4];
        #pragma unroll
        for (int tt = 0; tt < 4; ++tt) {
            const int tb = base + tt * 16;
            const float q0 = pos[3*(tb+col)], q1 = pos[3*(tb+col)+1], q2 = pos[3*(tb+col)+2];
            const float v = (g == 0) ? q0 : (g == 1) ? q1 : (g == 2) ? q2 : 1.0f;
            pBf[tt] = frag1(pack2bf(v, 0.0f));
        }

        // ---- gathers: 4 independent streams ----
        float fvA[4][4], fvB[4][4];
        #pragma unroll
        for (int tt = 0; tt < 4; ++tt) {
            const int tb = base + tt * 16;
            #pragma unroll
            for (int r = 0; r < 4; ++r) {
                const int2 mp = map2[tb + g*4 + r];
                const int my = mp.x, mx = mp.y;
                int y  = my + dyA, x  = mx + dxA;
                int yc = min(max(y,0),511), xc = min(max(x,0),511);
                float f = fbaseA[yc*512 + xc];
                fvA[tt][r] = (((unsigned)y | (unsigned)x) < 512u) ? f : 0.f;
                int y2 = my + dyB, x2 = mx + dxB;
                int yc2 = min(max(y2,0),511), xc2 = min(max(x2,0),511);
                float f2 = fbaseB[yc2*512 + xc2];
                fvB[tt][r] = (((unsigned)y2 | (unsigned)x2) < 512u) ? f2 : 0.f;
            }
        }

        f32x4 accA[4], accB[4];
        #pragma unroll
        for (int tt = 0; tt < 4; ++tt) {
            accA[tt] = (f32x4){b2A, b2A, b2A, b2A};
            accB[tt] = (f32x4){b2B, b2B, b2B, b2B};
        }
        const f32x4 zero = {0.f, 0.f, 0.f, 0.f};

        #pragma unroll
        for (int kc = 0; kc < 8; ++kc) {
            const bf16x8 wA0 = frag1(sW1f[2*kc    ][lane]);
            const bf16x8 wA1 = frag1(sW1f[2*kc + 1][lane]);
            const bf16x8 bv0 = sB[kc*2    ][lane];
            const bf16x8 bv1 = sB[kc*2 + 1][lane];

            #pragma unroll
            for (int tt = 0; tt < 4; ++tt) {
                // L1: h[j][px]; lane holds j = 16jt + 4g + reg, px = col
                const f32x4 c0 = __builtin_amdgcn_mfma_f32_16x16x32_bf16(wA0, pBf[tt], zero, 0,0,0);
                const f32x4 c1 = __builtin_amdgcn_mfma_f32_16x16x32_bf16(wA1, pBf[tt], zero, 0,0,0);
                // leaky + pack -> L2 A-fragment
                u32x4 a;
                a[0] = pack2bf(lk(c0[0]), lk(c0[1]));
                a[1] = pack2bf(lk(c0[2]), lk(c0[3]));
                a[2] = pack2bf(lk(c1[0]), lk(c1[1]));
                a[3] = pack2bf(lk(c1[2]), lk(c1[3]));
                const bf16x8 av = as_bf16x8(a);
                accA[tt] = __builtin_amdgcn_mfma_f32_16x16x32_bf16(av, bv0, accA[tt], 0,0,0);
                accB[tt] = __builtin_amdgcn_mfma_f32_16x16x32_bf16(av, bv1, accB[tt], 0,0,0);
            }
        }

        // ---- combine: col=lane&15 (k27), row=g*4+r (pixel); DPP 16-lane sum ----
        #pragma unroll
        for (int tt = 0; tt < 4; ++tt) {
            const int tb = base + tt * 16;
            #pragma unroll
            for (int r = 0; r < 4; ++r) {
                float s = accA[tt][r] * fvA[tt][r] + accB[tt][r] * fvB[tt][r];
                DPP_ADD(s, 0xB1);    // quad_perm(1,0,3,2) : xor 1
                DPP_ADD(s, 0x4E);    // quad_perm(2,3,0,1) : xor 2
                DPP_ADD(s, 0x124);   // row_ror:4
                DPP_ADD(s, 0x128);   // row_ror:8
                if (col == r) out[tb + g*4 + r] = s;
            }
        }
    }
}

extern "C" void kernel_launch(void* const* d_in, const int* in_sizes, int n_in,
                              void* d_out, int out_size, void* d_ws, size_t ws_size,
                              hipStream_t stream) {
    const float* pos     = (const float*)d_in[0];
    const int*   mapping = (const int*)d_in[1];
    const float* feats   = (const float*)d_in[2];
    // d_in[3] = depth, unused
    const float* W1      = (const float*)d_in[4];
    const float* b1      = (const float*)d_in[5];
    const float* W2      = (const float*)d_in[6];
    const float* b2      = (const float*)d_in[7];
    float* out = (float*)d_out;

    // P = 1024*1024: 65536 tiles; 2048 blocks x 4 waves x 2 iters x 4 tiles
    mapnet_v13<<<2048, 256, 0, stream>>>(pos, mapping, feats, W1, b1, W2, b2, out);
}

// Round 15
// 102.148 us; speedup vs baseline: 1.1309x; 1.1309x over previous
//
#include <hip/hip_runtime.h>

#define HID 256
#define K27 27

typedef __attribute__((ext_vector_type(8))) short    bf16x8;
typedef __attribute__((ext_vector_type(4))) float    f32x4;
typedef __attribute__((ext_vector_type(4))) unsigned u32x4;

static __device__ __forceinline__ unsigned short f2bf(float f) {
    union { float f; unsigned u; } v; v.f = f;   // cold path only (staging)
    return (unsigned short)((v.u + 0x7FFFu + ((v.u >> 16) & 1u)) >> 16);
}
static __device__ __forceinline__ unsigned pack2bf(float lo, float hi) {
    unsigned r;
    asm("v_cvt_pk_bf16_f32 %0, %1, %2" : "=v"(r) : "v"(lo), "v"(hi));
    return r;
}
static __device__ __forceinline__ bf16x8 as_bf16x8(u32x4 u) {
    return __builtin_bit_cast(bf16x8, u);
}
static __device__ __forceinline__ bf16x8 frag1(unsigned u) {
    u32x4 t = {u, 0u, 0u, 0u};
    return __builtin_bit_cast(bf16x8, t);
}
static __device__ __forceinline__ float lk(float x) {   // leaky_relu(0.01)
    return fmaxf(x, 0.01f * x);
}
// s += dpp_perm(s): VALU-only cross-lane add (verified v7/v10)
#define DPP_ADD(s, ctrl) \
    s += __builtin_bit_cast(float, __builtin_amdgcn_update_dpp( \
            0, __builtin_bit_cast(int, s), ctrl, 0xF, 0xF, true))

// v14 = v13 with ONE change: __launch_bounds__(256) without the min-occupancy
// arg. Diagnosis: every (256,4)-compiled variant pinned arch-VGPRs at 64 and
// sent the rest to scratch (v7/v12/v13 all showed FETCH/WRITE blowups at
// VGPR_Count=64). Dropping the cap lets the 4-tile ILP body live in registers.
__global__ __launch_bounds__(256) void mapnet_v14(
    const float* __restrict__ pos,      // (P,3)
    const int*   __restrict__ mapping,  // (P,2)
    const float* __restrict__ feats,    // (3,512,512)
    const float* __restrict__ W1,       // (256,3)
    const float* __restrict__ b1,       // (256)
    const float* __restrict__ W2,       // (27,256)
    const float* __restrict__ b2,       // (27)
    float* __restrict__ out)            // (P)
{
    __shared__ unsigned sW1f[16][64];   // [jt][lane]: pack2bf(W1val,0)  (4 KB)
    __shared__ bf16x8   sB[16][64];     // [kc*2+nt][lane]: L2 B-frags   (16 KB)

    const int tid = threadIdx.x;

    // ---- stage L1 A-fragments: lane (g,cc) of tile jt holds W1[16jt+cc][g] (g=3 -> b1)
    for (int e = tid; e < 1024; e += 256) {
        const int jt = e >> 6, l = e & 63;
        const int gg = l >> 4, cc = l & 15;
        const int j = jt * 16 + cc;
        const float val = (gg < 3) ? W1[3 * j + gg] : b1[j];
        sW1f[jt][l] = pack2bf(val, 0.0f);
    }
    // ---- stage L2 B-fragments, j-map matching L1 output: j = 32kc+16(e>>2)+4g+(e&3)
    for (int e = tid; e < 1024; e += 256) {
        const int kcnt = e >> 6, l = e & 63;
        const int kc = kcnt >> 1, nt = kcnt & 1;
        const int gg = l >> 4, cc = l & 15;
        const int n = nt * 16 + cc;
        const int jbase = kc * 32 + 4 * gg;
        u32x4 bb;
        #pragma unroll
        for (int i = 0; i < 4; ++i) {
            const int jlo = jbase + 16 * (i >> 1) + 2 * (i & 1);
            float f0 = 0.f, f1 = 0.f;
            if (n < K27) { f0 = W2[n * HID + jlo]; f1 = W2[n * HID + jlo + 1]; }
            bb[i] = (unsigned)f2bf(f0) | ((unsigned)f2bf(f1) << 16);
        }
        sB[kcnt][l] = as_bf16x8(bb);
    }
    __syncthreads();

    const int lane = tid & 63, wid = tid >> 6;
    const int g = lane >> 4, col = lane & 15;

    const float b2A = b2[col];
    const float b2B = (col < K27 - 16) ? b2[16 + col] : 0.0f;
    const int kA = col;
    const int cA = kA/9, dyA = (kA%9)/3 - 1, dxA = (kA%9)%3 - 1;
    const int kB = min(16 + col, K27 - 1);          // clamped -> valid addr; accB==0 there
    const int cB = kB/9, dyB = (kB%9)/3 - 1, dxB = (kB%9)%3 - 1;

    const float* fbaseA = feats + cA * (512*512);
    const float* fbaseB = feats + cB * (512*512);
    const int2*  map2   = (const int2*)mapping;

    const int w = blockIdx.x * 4 + wid;             // 0..8191

    for (int it = 0; it < 2; ++it) {
        const int base = (w * 8 + it * 4) * 16;     // 4 tiles of 16 px this iter

        // ---- L1 B-fragments (pos), one per tile ----
        bf16x8 pBf[4];
        #pragma unroll
        for (int tt = 0; tt < 4; ++tt) {
            const int tb = base + tt * 16;
            const float q0 = pos[3*(tb+col)], q1 = pos[3*(tb+col)+1], q2 = pos[3*(tb+col)+2];
            const float v = (g == 0) ? q0 : (g == 1) ? q1 : (g == 2) ? q2 : 1.0f;
            pBf[tt] = frag1(pack2bf(v, 0.0f));
        }

        // ---- gathers: 4 independent streams ----
        float fvA[4][4], fvB[4][4];
        #pragma unroll
        for (int tt = 0; tt < 4; ++tt) {
            const int tb = base + tt * 16;
            #pragma unroll
            for (int r = 0; r < 4; ++r) {
                const int2 mp = map2[tb + g*4 + r];
                const int my = mp.x, mx = mp.y;
                int y  = my + dyA, x  = mx + dxA;
                int yc = min(max(y,0),511), xc = min(max(x,0),511);
                float f = fbaseA[yc*512 + xc];
                fvA[tt][r] = (((unsigned)y | (unsigned)x) < 512u) ? f : 0.f;
                int y2 = my + dyB, x2 = mx + dxB;
                int yc2 = min(max(y2,0),511), xc2 = min(max(x2,0),511);
                float f2 = fbaseB[yc2*512 + xc2];
                fvB[tt][r] = (((unsigned)y2 | (unsigned)x2) < 512u) ? f2 : 0.f;
            }
        }

        f32x4 accA[4], accB[4];
        #pragma unroll
        for (int tt = 0; tt < 4; ++tt) {
            accA[tt] = (f32x4){b2A, b2A, b2A, b2A};
            accB[tt] = (f32x4){b2B, b2B, b2B, b2B};
        }
        const f32x4 zero = {0.f, 0.f, 0.f, 0.f};

        #pragma unroll
        for (int kc = 0; kc < 8; ++kc) {
            const bf16x8 wA0 = frag1(sW1f[2*kc    ][lane]);
            const bf16x8 wA1 = frag1(sW1f[2*kc + 1][lane]);
            const bf16x8 bv0 = sB[kc*2    ][lane];
            const bf16x8 bv1 = sB[kc*2 + 1][lane];

            #pragma unroll
            for (int tt = 0; tt < 4; ++tt) {
                // L1: h[j][px]; lane holds j = 16jt + 4g + reg, px = col
                const f32x4 c0 = __builtin_amdgcn_mfma_f32_16x16x32_bf16(wA0, pBf[tt], zero, 0,0,0);
                const f32x4 c1 = __builtin_amdgcn_mfma_f32_16x16x32_bf16(wA1, pBf[tt], zero, 0,0,0);
                // leaky + pack -> L2 A-fragment
                u32x4 a;
                a[0] = pack2bf(lk(c0[0]), lk(c0[1]));
                a[1] = pack2bf(lk(c0[2]), lk(c0[3]));
                a[2] = pack2bf(lk(c1[0]), lk(c1[1]));
                a[3] = pack2bf(lk(c1[2]), lk(c1[3]));
                const bf16x8 av = as_bf16x8(a);
                accA[tt] = __builtin_amdgcn_mfma_f32_16x16x32_bf16(av, bv0, accA[tt], 0,0,0);
                accB[tt] = __builtin_amdgcn_mfma_f32_16x16x32_bf16(av, bv1, accB[tt], 0,0,0);
            }
        }

        // ---- combine: col=lane&15 (k27), row=g*4+r (pixel); DPP 16-lane sum ----
        #pragma unroll
        for (int tt = 0; tt < 4; ++tt) {
            const int tb = base + tt * 16;
            #pragma unroll
            for (int r = 0; r < 4; ++r) {
                float s = accA[tt][r] * fvA[tt][r] + accB[tt][r] * fvB[tt][r];
                DPP_ADD(s, 0xB1);    // quad_perm(1,0,3,2) : xor 1
                DPP_ADD(s, 0x4E);    // quad_perm(2,3,0,1) : xor 2
                DPP_ADD(s, 0x124);   // row_ror:4
                DPP_ADD(s, 0x128);   // row_ror:8
                if (col == r) out[tb + g*4 + r] = s;
            }
        }
    }
}

extern "C" void kernel_launch(void* const* d_in, const int* in_sizes, int n_in,
                              void* d_out, int out_size, void* d_ws, size_t ws_size,
                              hipStream_t stream) {
    const float* pos     = (const float*)d_in[0];
    const int*   mapping = (const int*)d_in[1];
    const float* feats   = (const float*)d_in[2];
    // d_in[3] = depth, unused
    const float* W1      = (const float*)d_in[4];
    const float* b1      = (const float*)d_in[5];
    const float* W2      = (const float*)d_in[6];
    const float* b2      = (const float*)d_in[7];
    float* out = (float*)d_out;

    // P = 1024*1024: 65536 tiles; 2048 blocks x 4 waves x 2 iters x 4 tiles
    mapnet_v14<<<2048, 256, 0, stream>>>(pos, mapping, feats, W1, b1, W2, b2, out);
}

// Round 16
// 93.196 us; speedup vs baseline: 1.2395x; 1.0960x over previous
//
#include <hip/hip_runtime.h>

#define HID 256
#define K27 27

typedef __attribute__((ext_vector_type(8))) short    bf16x8;
typedef __attribute__((ext_vector_type(4))) float    f32x4;
typedef __attribute__((ext_vector_type(4))) unsigned u32x4;

static __device__ __forceinline__ unsigned short f2bf(float f) {
    union { float f; unsigned u; } v; v.f = f;   // cold path only (staging)
    return (unsigned short)((v.u + 0x7FFFu + ((v.u >> 16) & 1u)) >> 16);
}
static __device__ __forceinline__ unsigned pack2bf(float lo, float hi) {
    unsigned r;
    asm("v_cvt_pk_bf16_f32 %0, %1, %2" : "=v"(r) : "v"(lo), "v"(hi));
    return r;
}
static __device__ __forceinline__ bf16x8 as_bf16x8(u32x4 u) {
    return __builtin_bit_cast(bf16x8, u);
}
static __device__ __forceinline__ bf16x8 frag1(unsigned u) {
    u32x4 t = {u, 0u, 0u, 0u};
    return __builtin_bit_cast(bf16x8, t);
}
// s += dpp_perm(s): VALU-only cross-lane add (verified v7/v10)
#define DPP_ADD(s, ctrl) \
    s += __builtin_bit_cast(float, __builtin_amdgcn_update_dpp( \
            0, __builtin_bit_cast(int, s), ctrl, 0xF, 0xF, true))

// v15 = v10 with the leaky nonlinearity deleted algebraically:
//   leaky(z) = 0.505 z + 0.495 |z|, and |bf16x2(z)| = word & 0x7FFF7FFF.
// The kc loop packs z once (8 cvt_pk) and derives |z| by masking (8 v_and),
// accumulating W2.z and W2.|z| into separate MFMA accs; the combine applies
// lw = 0.505 accZ + 0.495 accAbs + b2. Identical math to W2.leaky(bf16(z))
// (for z<0 the 0.505/0.495 parts cancel in exact proportion). Removes the
// 32 max/mul per kc; +4 MFMA/kc rides the underused matrix pipe.
// Plain launch_bounds(256): the (256,4) variant pins 64 VGPR and spills.
__global__ __launch_bounds__(256) void mapnet_v15(
    const float* __restrict__ pos,      // (P,3)
    const int*   __restrict__ mapping,  // (P,2)
    const float* __restrict__ feats,    // (3,512,512)
    const float* __restrict__ W1,       // (256,3)
    const float* __restrict__ b1,       // (256)
    const float* __restrict__ W2,       // (27,256)
    const float* __restrict__ b2,       // (27)
    float* __restrict__ out)            // (P)
{
    __shared__ unsigned sW1f[16][64];   // [jt][lane]: pack2bf(W1val,0)  (4 KB)
    __shared__ bf16x8   sB[16][64];     // [kc*2+nt][lane]: L2 B-frags   (16 KB)

    const int tid = threadIdx.x;

    // ---- stage L1 A-fragments: lane (g,cc) of tile jt holds W1[16jt+cc][g] (g=3 -> b1)
    for (int e = tid; e < 1024; e += 256) {
        const int jt = e >> 6, l = e & 63;
        const int gg = l >> 4, cc = l & 15;
        const int j = jt * 16 + cc;
        const float val = (gg < 3) ? W1[3 * j + gg] : b1[j];
        sW1f[jt][l] = pack2bf(val, 0.0f);
    }
    // ---- stage L2 B-fragments, j-map matching L1 output: j = 32kc+16(e>>2)+4g+(e&3)
    for (int e = tid; e < 1024; e += 256) {
        const int kcnt = e >> 6, l = e & 63;
        const int kc = kcnt >> 1, nt = kcnt & 1;
        const int gg = l >> 4, cc = l & 15;
        const int n = nt * 16 + cc;
        const int jbase = kc * 32 + 4 * gg;
        u32x4 bb;
        #pragma unroll
        for (int i = 0; i < 4; ++i) {
            const int jlo = jbase + 16 * (i >> 1) + 2 * (i & 1);
            float f0 = 0.f, f1 = 0.f;
            if (n < K27) { f0 = W2[n * HID + jlo]; f1 = W2[n * HID + jlo + 1]; }
            bb[i] = (unsigned)f2bf(f0) | ((unsigned)f2bf(f1) << 16);
        }
        sB[kcnt][l] = as_bf16x8(bb);
    }
    __syncthreads();

    const int lane = tid & 63, wid = tid >> 6;
    const int g = lane >> 4, col = lane & 15;

    const float b2A = b2[col];
    const float b2B = (col < K27 - 16) ? b2[16 + col] : 0.0f;
    const int kA = col;
    const int cA = kA/9, dyA = (kA%9)/3 - 1, dxA = (kA%9)%3 - 1;
    const int kB = min(16 + col, K27 - 1);          // clamped -> valid addr; accB==0 there
    const int cB = kB/9, dyB = (kB%9)/3 - 1, dxB = (kB%9)%3 - 1;

    const float* fbaseA = feats + cA * (512*512);
    const float* fbaseB = feats + cB * (512*512);
    const int2*  map2   = (const int2*)mapping;

    const int w = blockIdx.x * 4 + wid;             // 0..8191

    for (int it = 0; it < 4; ++it) {
        const int tb0 = (w * 8 + it * 2) * 16, tb1 = tb0 + 16;

        const float q00 = pos[3*(tb0+col)], q01 = pos[3*(tb0+col)+1], q02 = pos[3*(tb0+col)+2];
        const float q10 = pos[3*(tb1+col)], q11 = pos[3*(tb1+col)+1], q12 = pos[3*(tb1+col)+2];
        const float v0 = (g == 0) ? q00 : (g == 1) ? q01 : (g == 2) ? q02 : 1.0f;
        const float v1 = (g == 0) ? q10 : (g == 1) ? q11 : (g == 2) ? q12 : 1.0f;
        const bf16x8 pB0 = frag1(pack2bf(v0, 0.0f));
        const bf16x8 pB1 = frag1(pack2bf(v1, 0.0f));

        // ---- gathers issued early (latency hides under the MFMA pipeline) ----
        float fvA[2][4], fvB[2][4];
        #pragma unroll
        for (int tt = 0; tt < 2; ++tt) {
            const int tb = tt ? tb1 : tb0;
            #pragma unroll
            for (int r = 0; r < 4; ++r) {
                const int2 mp = map2[tb + g*4 + r];
                const int my = mp.x, mx = mp.y;
                int y  = my + dyA, x  = mx + dxA;
                int yc = min(max(y,0),511), xc = min(max(x,0),511);
                float f = fbaseA[yc*512 + xc];
                fvA[tt][r] = (((unsigned)y | (unsigned)x) < 512u) ? f : 0.f;
                int y2 = my + dyB, x2 = mx + dxB;
                int yc2 = min(max(y2,0),511), xc2 = min(max(x2,0),511);
                float f2 = fbaseB[yc2*512 + xc2];
                fvB[tt][r] = (((unsigned)y2 | (unsigned)x2) < 512u) ? f2 : 0.f;
            }
        }

        const f32x4 zero = {0.f, 0.f, 0.f, 0.f};
        f32x4 zc00 = zero, zc01 = zero, zc10 = zero, zc11 = zero;   // W2 . z
        f32x4 ac00 = zero, ac01 = zero, ac10 = zero, ac11 = zero;   // W2 . |z|

        #pragma unroll
        for (int kc = 0; kc < 8; ++kc) {
            const bf16x8 wA0 = frag1(sW1f[2*kc    ][lane]);
            const bf16x8 wA1 = frag1(sW1f[2*kc + 1][lane]);

            // L1: z[j][px]; lane holds j = 16jt + 4g + reg, px = col
            const f32x4 c00 = __builtin_amdgcn_mfma_f32_16x16x32_bf16(wA0, pB0, zero, 0,0,0);
            const f32x4 c01 = __builtin_amdgcn_mfma_f32_16x16x32_bf16(wA1, pB0, zero, 0,0,0);
            const f32x4 c10 = __builtin_amdgcn_mfma_f32_16x16x32_bf16(wA0, pB1, zero, 0,0,0);
            const f32x4 c11 = __builtin_amdgcn_mfma_f32_16x16x32_bf16(wA1, pB1, zero, 0,0,0);

            // pack z -> L2 A-fragment; |z| by masking both bf16 sign bits
            u32x4 a0, a1;
            a0[0] = pack2bf(c00[0], c00[1]);
            a0[1] = pack2bf(c00[2], c00[3]);
            a0[2] = pack2bf(c01[0], c01[1]);
            a0[3] = pack2bf(c01[2], c01[3]);
            a1[0] = pack2bf(c10[0], c10[1]);
            a1[1] = pack2bf(c10[2], c10[3]);
            a1[2] = pack2bf(c11[0], c11[1]);
            a1[3] = pack2bf(c11[2], c11[3]);
            u32x4 m0, m1;
            #pragma unroll
            for (int i = 0; i < 4; ++i) { m0[i] = a0[i] & 0x7FFF7FFFu; m1[i] = a1[i] & 0x7FFF7FFFu; }
            const bf16x8 av0 = as_bf16x8(a0);
            const bf16x8 av1 = as_bf16x8(a1);
            const bf16x8 am0 = as_bf16x8(m0);
            const bf16x8 am1 = as_bf16x8(m1);

            const bf16x8 bv0 = sB[kc*2    ][lane];
            const bf16x8 bv1 = sB[kc*2 + 1][lane];
            zc00 = __builtin_amdgcn_mfma_f32_16x16x32_bf16(av0, bv0, zc00, 0,0,0);
            zc01 = __builtin_amdgcn_mfma_f32_16x16x32_bf16(av0, bv1, zc01, 0,0,0);
            zc10 = __builtin_amdgcn_mfma_f32_16x16x32_bf16(av1, bv0, zc10, 0,0,0);
            zc11 = __builtin_amdgcn_mfma_f32_16x16x32_bf16(av1, bv1, zc11, 0,0,0);
            ac00 = __builtin_amdgcn_mfma_f32_16x16x32_bf16(am0, bv0, ac00, 0,0,0);
            ac01 = __builtin_amdgcn_mfma_f32_16x16x32_bf16(am0, bv1, ac01, 0,0,0);
            ac10 = __builtin_amdgcn_mfma_f32_16x16x32_bf16(am1, bv0, ac10, 0,0,0);
            ac11 = __builtin_amdgcn_mfma_f32_16x16x32_bf16(am1, bv1, ac11, 0,0,0);
        }

        // ---- combine: lw = 0.505 accZ + 0.495 accAbs + b2; DPP 16-lane sum ----
        #pragma unroll
        for (int tt = 0; tt < 2; ++tt) {
            const int tb = tt ? tb1 : tb0;
            const f32x4 zA = tt ? zc10 : zc00;
            const f32x4 zB = tt ? zc11 : zc01;
            const f32x4 aA = tt ? ac10 : ac00;
            const f32x4 aB = tt ? ac11 : ac01;
            #pragma unroll
            for (int r = 0; r < 4; ++r) {
                const float lwA = fmaf(0.505f, zA[r], fmaf(0.495f, aA[r], b2A));
                const float lwB = fmaf(0.505f, zB[r], fmaf(0.495f, aB[r], b2B));
                float s = fmaf(lwB, fvB[tt][r], lwA * fvA[tt][r]);
                DPP_ADD(s, 0xB1);    // quad_perm(1,0,3,2) : xor 1
                DPP_ADD(s, 0x4E);    // quad_perm(2,3,0,1) : xor 2
                DPP_ADD(s, 0x124);   // row_ror:4
                DPP_ADD(s, 0x128);   // row_ror:8
                if (col == r) out[tb + g*4 + r] = s;
            }
        }
    }
}

extern "C" void kernel_launch(void* const* d_in, const int* in_sizes, int n_in,
                              void* d_out, int out_size, void* d_ws, size_t ws_size,
                              hipStream_t stream) {
    const float* pos     = (const float*)d_in[0];
    const int*   mapping = (const int*)d_in[1];
    const float* feats   = (const float*)d_in[2];
    // d_in[3] = depth, unused
    const float* W1      = (const float*)d_in[4];
    const float* b1      = (const float*)d_in[5];
    const float* W2      = (const float*)d_in[6];
    const float* b2      = (const float*)d_in[7];
    float* out = (float*)d_out;

    // P = 1024*1024: 65536 tiles; 2048 blocks x 4 waves x 8 tiles
    mapnet_v15<<<2048, 256, 0, stream>>>(pos, mapping, feats, W1, b1, W2, b2, out);
}

// Round 17
// 71.871 us; speedup vs baseline: 1.6073x; 1.2967x over previous
//
#include <hip/hip_runtime.h>

#define HID 256
#define K27 27

typedef __attribute__((ext_vector_type(8))) short    bf16x8;
typedef __attribute__((ext_vector_type(4))) float    f32x4;
typedef __attribute__((ext_vector_type(4))) unsigned u32x4;

static __device__ __forceinline__ unsigned short f2bf(float f) {
    union { float f; unsigned u; } v; v.f = f;   // cold path only (staging)
    return (unsigned short)((v.u + 0x7FFFu + ((v.u >> 16) & 1u)) >> 16);
}
static __device__ __forceinline__ unsigned pack2bf(float lo, float hi) {
    unsigned r;
    asm("v_cvt_pk_bf16_f32 %0, %1, %2" : "=v"(r) : "v"(lo), "v"(hi));
    return r;
}
static __device__ __forceinline__ bf16x8 as_bf16x8(u32x4 u) {
    return __builtin_bit_cast(bf16x8, u);
}
static __device__ __forceinline__ bf16x8 frag1(unsigned u) {
    u32x4 t = {u, 0u, 0u, 0u};
    return __builtin_bit_cast(bf16x8, t);
}
static __device__ __forceinline__ float lk(float x) {   // leaky_relu(0.01)
    return fmaxf(x, 0.01f * x);
}
// s += dpp_perm(s): VALU-only cross-lane add (verified v7/v10)
#define DPP_ADD(s, ctrl) \
    s += __builtin_bit_cast(float, __builtin_amdgcn_update_dpp( \
            0, __builtin_bit_cast(int, s), ctrl, 0xF, 0xF, true))

// one-time setup: pre-assemble the LDS fragment images into d_ws.
// ws layout: [0,4096) = sW1f words (1024 u32); [4096, 20480) = sB frags
// (1024 x 16B). Uncoalesced W2 reads happen ONCE here instead of per-block.
__global__ __launch_bounds__(256) void setup_frags(
    const float* __restrict__ W1, const float* __restrict__ b1,
    const float* __restrict__ W2,
    unsigned* __restrict__ wsW1, u32x4* __restrict__ wsB)
{
    const int e = blockIdx.x * 256 + threadIdx.x;   // 0..2047
    if (e < 1024) {
        // sW1f word e: jt=e>>6, l=e&63; lane (gg,cc) of tile jt holds W1[16jt+cc][gg] (gg=3 -> b1)
        const int l = e & 63;
        const int gg = l >> 4, cc = l & 15;
        const int j = (e >> 6) * 16 + cc;
        const float val = (gg < 3) ? W1[3 * j + gg] : b1[j];
        wsW1[e] = (unsigned)f2bf(val);              // == pack2bf(val, 0)
    } else {
        // sB fragment f: kcnt=f>>6, l=f&63; j-map j = 32kc+16(i>>1 block)+...
        const int f = e - 1024;
        const int kcnt = f >> 6, l = f & 63;
        const int kc = kcnt >> 1, nt = kcnt & 1;
        const int gg = l >> 4, cc = l & 15;
        const int n = nt * 16 + cc;
        const int jbase = kc * 32 + 4 * gg;
        u32x4 bb;
        #pragma unroll
        for (int i = 0; i < 4; ++i) {
            const int jlo = jbase + 16 * (i >> 1) + 2 * (i & 1);
            float f0 = 0.f, f1 = 0.f;
            if (n < K27) { f0 = W2[n * HID + jlo]; f1 = W2[n * HID + jlo + 1]; }
            bb[i] = (unsigned)f2bf(f0) | ((unsigned)f2bf(f1) << 16);
        }
        wsB[f] = bb;
    }
}

// v16 = v10 (verified 78us) with ONE change: LDS staging loads pre-assembled
// fragment images from d_ws (coalesced: 4 dword + 4 b128 per thread) instead
// of rebuilding them from W1/W2 with ~64-way-uncoalesced reads in every one
// of the 2048 blocks. use_ws=0 falls back to v10's exact staging.
__global__ __launch_bounds__(256, 4) void mapnet_v16(
    const float* __restrict__ pos,      // (P,3)
    const int*   __restrict__ mapping,  // (P,2)
    const float* __restrict__ feats,    // (3,512,512)
    const float* __restrict__ W1,       // (256,3)
    const float* __restrict__ b1,       // (256)
    const float* __restrict__ W2,       // (27,256)
    const float* __restrict__ b2,       // (27)
    float* __restrict__ out,            // (P)
    int use_ws,
    const unsigned* __restrict__ wsW1,  // 1024 u32
    const u32x4*    __restrict__ wsB)   // 1024 x 16B
{
    __shared__ unsigned sW1f[16][64];   // [jt][lane]: pack2bf(W1val,0)  (4 KB)
    __shared__ bf16x8   sB[16][64];     // [kc*2+nt][lane]: L2 B-frags   (16 KB)

    const int tid = threadIdx.x;

    if (use_ws) {
        // coalesced image copy: 4 dwords + 4 x 16B per thread
        unsigned* s1 = &sW1f[0][0];
        u32x4*    s2 = reinterpret_cast<u32x4*>(&sB[0][0]);
        #pragma unroll
        for (int k = 0; k < 4; ++k) {
            const int e = k * 256 + tid;
            s1[e] = wsW1[e];
            s2[e] = wsB[e];
        }
    } else {
        // v10's original staging (fallback when ws is too small)
        for (int e = tid; e < 1024; e += 256) {
            const int jt = e >> 6, l = e & 63;
            const int gg = l >> 4, cc = l & 15;
            const int j = jt * 16 + cc;
            const float val = (gg < 3) ? W1[3 * j + gg] : b1[j];
            sW1f[jt][l] = pack2bf(val, 0.0f);
        }
        for (int e = tid; e < 1024; e += 256) {
            const int kcnt = e >> 6, l = e & 63;
            const int kc = kcnt >> 1, nt = kcnt & 1;
            const int gg = l >> 4, cc = l & 15;
            const int n = nt * 16 + cc;
            const int jbase = kc * 32 + 4 * gg;
            u32x4 bb;
            #pragma unroll
            for (int i = 0; i < 4; ++i) {
                const int jlo = jbase + 16 * (i >> 1) + 2 * (i & 1);
                float f0 = 0.f, f1 = 0.f;
                if (n < K27) { f0 = W2[n * HID + jlo]; f1 = W2[n * HID + jlo + 1]; }
                bb[i] = (unsigned)f2bf(f0) | ((unsigned)f2bf(f1) << 16);
            }
            sB[kcnt][l] = as_bf16x8(bb);
        }
    }
    __syncthreads();

    const int lane = tid & 63, wid = tid >> 6;
    const int g = lane >> 4, col = lane & 15;

    const float b2A = b2[col];
    const float b2B = (col < K27 - 16) ? b2[16 + col] : 0.0f;
    const int kA = col;
    const int cA = kA/9, dyA = (kA%9)/3 - 1, dxA = (kA%9)%3 - 1;
    const int kB = min(16 + col, K27 - 1);          // clamped -> valid addr; accB==0 there
    const int cB = kB/9, dyB = (kB%9)/3 - 1, dxB = (kB%9)%3 - 1;

    const float* fbaseA = feats + cA * (512*512);
    const float* fbaseB = feats + cB * (512*512);
    const int2*  map2   = (const int2*)mapping;

    const int w = blockIdx.x * 4 + wid;             // 0..8191

    for (int it = 0; it < 4; ++it) {
        const int tb0 = (w * 8 + it * 2) * 16, tb1 = tb0 + 16;

        const float q00 = pos[3*(tb0+col)], q01 = pos[3*(tb0+col)+1], q02 = pos[3*(tb0+col)+2];
        const float q10 = pos[3*(tb1+col)], q11 = pos[3*(tb1+col)+1], q12 = pos[3*(tb1+col)+2];
        const float v0 = (g == 0) ? q00 : (g == 1) ? q01 : (g == 2) ? q02 : 1.0f;
        const float v1 = (g == 0) ? q10 : (g == 1) ? q11 : (g == 2) ? q12 : 1.0f;
        const bf16x8 pB0 = frag1(pack2bf(v0, 0.0f));
        const bf16x8 pB1 = frag1(pack2bf(v1, 0.0f));

        // ---- gathers issued early (latency hides under the MFMA pipeline) ----
        float fvA[2][4], fvB[2][4];
        #pragma unroll
        for (int tt = 0; tt < 2; ++tt) {
            const int tb = tt ? tb1 : tb0;
            #pragma unroll
            for (int r = 0; r < 4; ++r) {
                const int2 mp = map2[tb + g*4 + r];
                const int my = mp.x, mx = mp.y;
                int y  = my + dyA, x  = mx + dxA;
                int yc = min(max(y,0),511), xc = min(max(x,0),511);
                float f = fbaseA[yc*512 + xc];
                fvA[tt][r] = (((unsigned)y | (unsigned)x) < 512u) ? f : 0.f;
                int y2 = my + dyB, x2 = mx + dxB;
                int yc2 = min(max(y2,0),511), xc2 = min(max(x2,0),511);
                float f2 = fbaseB[yc2*512 + xc2];
                fvB[tt][r] = (((unsigned)y2 | (unsigned)x2) < 512u) ? f2 : 0.f;
            }
        }

        f32x4 acc00 = {b2A,b2A,b2A,b2A}, acc01 = {b2B,b2B,b2B,b2B};
        f32x4 acc10 = {b2A,b2A,b2A,b2A}, acc11 = {b2B,b2B,b2B,b2B};
        const f32x4 zero = {0.f, 0.f, 0.f, 0.f};

        #pragma unroll
        for (int kc = 0; kc < 8; ++kc) {
            const bf16x8 wA0 = frag1(sW1f[2*kc    ][lane]);
            const bf16x8 wA1 = frag1(sW1f[2*kc + 1][lane]);

            // L1: h[j][px]; lane holds j = 16jt + 4g + reg, px = col
            const f32x4 c00 = __builtin_amdgcn_mfma_f32_16x16x32_bf16(wA0, pB0, zero, 0,0,0);
            const f32x4 c01 = __builtin_amdgcn_mfma_f32_16x16x32_bf16(wA1, pB0, zero, 0,0,0);
            const f32x4 c10 = __builtin_amdgcn_mfma_f32_16x16x32_bf16(wA0, pB1, zero, 0,0,0);
            const f32x4 c11 = __builtin_amdgcn_mfma_f32_16x16x32_bf16(wA1, pB1, zero, 0,0,0);

            // leaky + pack -> L2 A-fragment
            u32x4 a0, a1;
            a0[0] = pack2bf(lk(c00[0]), lk(c00[1]));
            a0[1] = pack2bf(lk(c00[2]), lk(c00[3]));
            a0[2] = pack2bf(lk(c01[0]), lk(c01[1]));
            a0[3] = pack2bf(lk(c01[2]), lk(c01[3]));
            a1[0] = pack2bf(lk(c10[0]), lk(c10[1]));
            a1[1] = pack2bf(lk(c10[2]), lk(c10[3]));
            a1[2] = pack2bf(lk(c11[0]), lk(c11[1]));
            a1[3] = pack2bf(lk(c11[2]), lk(c11[3]));
            const bf16x8 av0 = as_bf16x8(a0);
            const bf16x8 av1 = as_bf16x8(a1);

            const bf16x8 bv0 = sB[kc*2    ][lane];
            const bf16x8 bv1 = sB[kc*2 + 1][lane];
            acc00 = __builtin_amdgcn_mfma_f32_16x16x32_bf16(av0, bv0, acc00, 0,0,0);
            acc01 = __builtin_amdgcn_mfma_f32_16x16x32_bf16(av0, bv1, acc01, 0,0,0);
            acc10 = __builtin_amdgcn_mfma_f32_16x16x32_bf16(av1, bv0, acc10, 0,0,0);
            acc11 = __builtin_amdgcn_mfma_f32_16x16x32_bf16(av1, bv1, acc11, 0,0,0);
        }

        // ---- combine: col=lane&15 (k27), row=g*4+r (pixel); DPP 16-lane sum ----
        #pragma unroll
        for (int tt = 0; tt < 2; ++tt) {
            const int tb = tt ? tb1 : tb0;
            const f32x4 aA = tt ? acc10 : acc00;
            const f32x4 aB = tt ? acc11 : acc01;
            #pragma unroll
            for (int r = 0; r < 4; ++r) {
                float s = aA[r] * fvA[tt][r] + aB[r] * fvB[tt][r];
                DPP_ADD(s, 0xB1);    // quad_perm(1,0,3,2) : xor 1
                DPP_ADD(s, 0x4E);    // quad_perm(2,3,0,1) : xor 2
                DPP_ADD(s, 0x124);   // row_ror:4
                DPP_ADD(s, 0x128);   // row_ror:8
                if (col == r) out[tb + g*4 + r] = s;
            }
        }
    }
}

extern "C" void kernel_launch(void* const* d_in, const int* in_sizes, int n_in,
                              void* d_out, int out_size, void* d_ws, size_t ws_size,
                              hipStream_t stream) {
    const float* pos     = (const float*)d_in[0];
    const int*   mapping = (const int*)d_in[1];
    const float* feats   = (const float*)d_in[2];
    // d_in[3] = depth, unused
    const float* W1      = (const float*)d_in[4];
    const float* b1      = (const float*)d_in[5];
    const float* W2      = (const float*)d_in[6];
    const float* b2      = (const float*)d_in[7];
    float* out = (float*)d_out;

    const size_t need = 4096 + 16384;               // 20.5 KB
    if (d_ws != nullptr && ws_size >= need) {
        unsigned* wsW1 = (unsigned*)d_ws;
        u32x4*    wsB  = (u32x4*)((char*)d_ws + 4096);
        setup_frags<<<8, 256, 0, stream>>>(W1, b1, W2, wsW1, wsB);
        mapnet_v16<<<2048, 256, 0, stream>>>(pos, mapping, feats, W1, b1, W2, b2, out,
                                             1, wsW1, wsB);
    } else {
        mapnet_v16<<<2048, 256, 0, stream>>>(pos, mapping, feats, W1, b1, W2, b2, out,
                                             0, nullptr, nullptr);
    }
}

// Round 19
// 71.140 us; speedup vs baseline: 1.6238x; 1.0103x over previous
//
#include <hip/hip_runtime.h>

#define HID 256
#define K27 27

typedef __attribute__((ext_vector_type(8))) short    bf16x8;
typedef __attribute__((ext_vector_type(4))) float    f32x4;
typedef __attribute__((ext_vector_type(4))) unsigned u32x4;

static __device__ __forceinline__ unsigned short f2bf(float f) {
    union { float f; unsigned u; } v; v.f = f;   // cold path only (staging)
    return (unsigned short)((v.u + 0x7FFFu + ((v.u >> 16) & 1u)) >> 16);
}
static __device__ __forceinline__ unsigned pack2bf(float lo, float hi) {
    unsigned r;
    asm("v_cvt_pk_bf16_f32 %0, %1, %2" : "=v"(r) : "v"(lo), "v"(hi));
    return r;
}
static __device__ __forceinline__ bf16x8 as_bf16x8(u32x4 u) {
    return __builtin_bit_cast(bf16x8, u);
}
static __device__ __forceinline__ bf16x8 frag1(unsigned u) {
    u32x4 t = {u, 0u, 0u, 0u};
    return __builtin_bit_cast(bf16x8, t);
}
static __device__ __forceinline__ float lk(float x) {   // leaky_relu(0.01)
    return fmaxf(x, 0.01f * x);
}
// s += dpp_perm(s): VALU-only cross-lane add (verified v7/v10/v16)
#define DPP_ADD(s, ctrl) \
    s += __builtin_bit_cast(float, __builtin_amdgcn_update_dpp( \
            0, __builtin_bit_cast(int, s), ctrl, 0xF, 0xF, true))

// one-time setup: pre-assemble the LDS fragment images into d_ws.
// ws layout: [0,4096) = sW1f words (1024 u32); [4096, 20480) = sB frags
// (1024 x 16B). Uncoalesced W2 reads happen ONCE here instead of per-block.
__global__ __launch_bounds__(256) void setup_frags(
    const float* __restrict__ W1, const float* __restrict__ b1,
    const float* __restrict__ W2,
    unsigned* __restrict__ wsW1, u32x4* __restrict__ wsB)
{
    const int e = blockIdx.x * 256 + threadIdx.x;   // 0..2047
    if (e < 1024) {
        // sW1f word e: jt=e>>6, l=e&63; lane (gg,cc) of tile jt holds W1[16jt+cc][gg] (gg=3 -> b1)
        const int l = e & 63;
        const int gg = l >> 4, cc = l & 15;
        const int j = (e >> 6) * 16 + cc;
        const float val = (gg < 3) ? W1[3 * j + gg] : b1[j];
        wsW1[e] = (unsigned)f2bf(val);              // == pack2bf(val, 0)
    } else {
        // sB fragment f: kcnt=f>>6, l=f&63; j-map j = 32kc+16(e>>2)+4g+(e&3)
        const int f = e - 1024;
        const int kcnt = f >> 6, l = f & 63;
        const int kc = kcnt >> 1, nt = kcnt & 1;
        const int gg = l >> 4, cc = l & 15;
        const int n = nt * 16 + cc;
        const int jbase = kc * 32 + 4 * gg;
        u32x4 bb;
        #pragma unroll
        for (int i = 0; i < 4; ++i) {
            const int jlo = jbase + 16 * (i >> 1) + 2 * (i & 1);
            float f0 = 0.f, f1 = 0.f;
            if (n < K27) { f0 = W2[n * HID + jlo]; f1 = W2[n * HID + jlo + 1]; }
            bb[i] = (unsigned)f2bf(f0) | ((unsigned)f2bf(f1) << 16);
        }
        wsB[f] = bb;
    }
}

// v18 = v16 verbatim (verified 71.9us): v10 main loop + pre-assembled LDS
// fragment images loaded coalesced from d_ws. Restored after v17's NaN
// (4th NaN from schedule-perturbing edits; every minimal-delta-on-verified
// variant has passed — this is the verified best state).
__global__ __launch_bounds__(256, 4) void mapnet_v16(
    const float* __restrict__ pos,      // (P,3)
    const int*   __restrict__ mapping,  // (P,2)
    const float* __restrict__ feats,    // (3,512,512)
    const float* __restrict__ W1,       // (256,3)
    const float* __restrict__ b1,       // (256)
    const float* __restrict__ W2,       // (27,256)
    const float* __restrict__ b2,       // (27)
    float* __restrict__ out,            // (P)
    int use_ws,
    const unsigned* __restrict__ wsW1,  // 1024 u32
    const u32x4*    __restrict__ wsB)   // 1024 x 16B
{
    __shared__ unsigned sW1f[16][64];   // [jt][lane]: pack2bf(W1val,0)  (4 KB)
    __shared__ bf16x8   sB[16][64];     // [kc*2+nt][lane]: L2 B-frags   (16 KB)

    const int tid = threadIdx.x;

    if (use_ws) {
        // coalesced image copy: 4 dwords + 4 x 16B per thread
        unsigned* s1 = &sW1f[0][0];
        u32x4*    s2 = reinterpret_cast<u32x4*>(&sB[0][0]);
        #pragma unroll
        for (int k = 0; k < 4; ++k) {
            const int e = k * 256 + tid;
            s1[e] = wsW1[e];
            s2[e] = wsB[e];
        }
    } else {
        // v10's original staging (fallback when ws is too small)
        for (int e = tid; e < 1024; e += 256) {
            const int jt = e >> 6, l = e & 63;
            const int gg = l >> 4, cc = l & 15;
            const int j = jt * 16 + cc;
            const float val = (gg < 3) ? W1[3 * j + gg] : b1[j];
            sW1f[jt][l] = pack2bf(val, 0.0f);
        }
        for (int e = tid; e < 1024; e += 256) {
            const int kcnt = e >> 6, l = e & 63;
            const int kc = kcnt >> 1, nt = kcnt & 1;
            const int gg = l >> 4, cc = l & 15;
            const int n = nt * 16 + cc;
            const int jbase = kc * 32 + 4 * gg;
            u32x4 bb;
            #pragma unroll
            for (int i = 0; i < 4; ++i) {
                const int jlo = jbase + 16 * (i >> 1) + 2 * (i & 1);
                float f0 = 0.f, f1 = 0.f;
                if (n < K27) { f0 = W2[n * HID + jlo]; f1 = W2[n * HID + jlo + 1]; }
                bb[i] = (unsigned)f2bf(f0) | ((unsigned)f2bf(f1) << 16);
            }
            sB[kcnt][l] = as_bf16x8(bb);
        }
    }
    __syncthreads();

    const int lane = tid & 63, wid = tid >> 6;
    const int g = lane >> 4, col = lane & 15;

    const float b2A = b2[col];
    const float b2B = (col < K27 - 16) ? b2[16 + col] : 0.0f;
    const int kA = col;
    const int cA = kA/9, dyA = (kA%9)/3 - 1, dxA = (kA%9)%3 - 1;
    const int kB = min(16 + col, K27 - 1);          // clamped -> valid addr; accB==0 there
    const int cB = kB/9, dyB = (kB%9)/3 - 1, dxB = (kB%9)%3 - 1;

    const float* fbaseA = feats + cA * (512*512);
    const float* fbaseB = feats + cB * (512*512);
    const int2*  map2   = (const int2*)mapping;

    const int w = blockIdx.x * 4 + wid;             // 0..8191

    for (int it = 0; it < 4; ++it) {
        const int tb0 = (w * 8 + it * 2) * 16, tb1 = tb0 + 16;

        const float q00 = pos[3*(tb0+col)], q01 = pos[3*(tb0+col)+1], q02 = pos[3*(tb0+col)+2];
        const float q10 = pos[3*(tb1+col)], q11 = pos[3*(tb1+col)+1], q12 = pos[3*(tb1+col)+2];
        const float v0 = (g == 0) ? q00 : (g == 1) ? q01 : (g == 2) ? q02 : 1.0f;
        const float v1 = (g == 0) ? q10 : (g == 1) ? q11 : (g == 2) ? q12 : 1.0f;
        const bf16x8 pB0 = frag1(pack2bf(v0, 0.0f));
        const bf16x8 pB1 = frag1(pack2bf(v1, 0.0f));

        // ---- gathers issued early (latency hides under the MFMA pipeline) ----
        float fvA[2][4], fvB[2][4];
        #pragma unroll
        for (int tt = 0; tt < 2; ++tt) {
            const int tb = tt ? tb1 : tb0;
            #pragma unroll
            for (int r = 0; r < 4; ++r) {
                const int2 mp = map2[tb + g*4 + r];
                const int my = mp.x, mx = mp.y;
                int y  = my + dyA, x  = mx + dxA;
                int yc = min(max(y,0),511), xc = min(max(x,0),511);
                float f = fbaseA[yc*512 + xc];
                fvA[tt][r] = (((unsigned)y | (unsigned)x) < 512u) ? f : 0.f;
                int y2 = my + dyB, x2 = mx + dxB;
                int yc2 = min(max(y2,0),511), xc2 = min(max(x2,0),511);
                float f2 = fbaseB[yc2*512 + xc2];
                fvB[tt][r] = (((unsigned)y2 | (unsigned)x2) < 512u) ? f2 : 0.f;
            }
        }

        f32x4 acc00 = {b2A,b2A,b2A,b2A}, acc01 = {b2B,b2B,b2B,b2B};
        f32x4 acc10 = {b2A,b2A,b2A,b2A}, acc11 = {b2B,b2B,b2B,b2B};
        const f32x4 zero = {0.f, 0.f, 0.f, 0.f};

        #pragma unroll
        for (int kc = 0; kc < 8; ++kc) {
            const bf16x8 wA0 = frag1(sW1f[2*kc    ][lane]);
            const bf16x8 wA1 = frag1(sW1f[2*kc + 1][lane]);

            // L1: h[j][px]; lane holds j = 16jt + 4g + reg, px = col
            const f32x4 c00 = __builtin_amdgcn_mfma_f32_16x16x32_bf16(wA0, pB0, zero, 0,0,0);
            const f32x4 c01 = __builtin_amdgcn_mfma_f32_16x16x32_bf16(wA1, pB0, zero, 0,0,0);
            const f32x4 c10 = __builtin_amdgcn_mfma_f32_16x16x32_bf16(wA0, pB1, zero, 0,0,0);
            const f32x4 c11 = __builtin_amdgcn_mfma_f32_16x16x32_bf16(wA1, pB1, zero, 0,0,0);

            // leaky + pack -> L2 A-fragment
            u32x4 a0, a1;
            a0[0] = pack2bf(lk(c00[0]), lk(c00[1]));
            a0[1] = pack2bf(lk(c00[2]), lk(c00[3]));
            a0[2] = pack2bf(lk(c01[0]), lk(c01[1]));
            a0[3] = pack2bf(lk(c01[2]), lk(c01[3]));
            a1[0] = pack2bf(lk(c10[0]), lk(c10[1]));
            a1[1] = pack2bf(lk(c10[2]), lk(c10[3]));
            a1[2] = pack2bf(lk(c11[0]), lk(c11[1]));
            a1[3] = pack2bf(lk(c11[2]), lk(c11[3]));
            const bf16x8 av0 = as_bf16x8(a0);
            const bf16x8 av1 = as_bf16x8(a1);

            const bf16x8 bv0 = sB[kc*2    ][lane];
            const bf16x8 bv1 = sB[kc*2 + 1][lane];
            acc00 = __builtin_amdgcn_mfma_f32_16x16x32_bf16(av0, bv0, acc00, 0,0,0);
            acc01 = __builtin_amdgcn_mfma_f32_16x16x32_bf16(av0, bv1, acc01, 0,0,0);
            acc10 = __builtin_amdgcn_mfma_f32_16x16x32_bf16(av1, bv0, acc10, 0,0,0);
            acc11 = __builtin_amdgcn_mfma_f32_16x16x32_bf16(av1, bv1, acc11, 0,0,0);
        }

        // ---- combine: col=lane&15 (k27), row=g*4+r (pixel); DPP 16-lane sum ----
        #pragma unroll
        for (int tt = 0; tt < 2; ++tt) {
            const int tb = tt ? tb1 : tb0;
            const f32x4 aA = tt ? acc10 : acc00;
            const f32x4 aB = tt ? acc11 : acc01;
            #pragma unroll
            for (int r = 0; r < 4; ++r) {
                float s = aA[r] * fvA[tt][r] + aB[r] * fvB[tt][r];
                DPP_ADD(s, 0xB1);    // quad_perm(1,0,3,2) : xor 1
                DPP_ADD(s, 0x4E);    // quad_perm(2,3,0,1) : xor 2
                DPP_ADD(s, 0x124);   // row_ror:4
                DPP_ADD(s, 0x128);   // row_ror:8
                if (col == r) out[tb + g*4 + r] = s;
            }
        }
    }
}

extern "C" void kernel_launch(void* const* d_in, const int* in_sizes, int n_in,
                              void* d_out, int out_size, void* d_ws, size_t ws_size,
                              hipStream_t stream) {
    const float* pos     = (const float*)d_in[0];
    const int*   mapping = (const int*)d_in[1];
    const float* feats   = (const float*)d_in[2];
    // d_in[3] = depth, unused
    const float* W1      = (const float*)d_in[4];
    const float* b1      = (const float*)d_in[5];
    const float* W2      = (const float*)d_in[6];
    const float* b2      = (const float*)d_in[7];
    float* out = (float*)d_out;

    const size_t need = 4096 + 16384;               // 20.5 KB
    if (d_ws != nullptr && ws_size >= need) {
        unsigned* wsW1 = (unsigned*)d_ws;
        u32x4*    wsB  = (u32x4*)((char*)d_ws + 4096);
        setup_frags<<<8, 256, 0, stream>>>(W1, b1, W2, wsW1, wsB);
        mapnet_v16<<<2048, 256, 0, stream>>>(pos, mapping, feats, W1, b1, W2, b2, out,
                                             1, wsW1, wsB);
    } else {
        mapnet_v16<<<2048, 256, 0, stream>>>(pos, mapping, feats, W1, b1, W2, b2, out,
                                             0, nullptr, nullptr);
    }
}